// Round 1
// baseline (3366.820 us; speedup 1.0000x reference)
//
#include <hip/hip_runtime.h>
#include <hip/hip_bf16.h>
#include <math.h>

#define S 1024
#define BATCH 8
#define DMODEL 256
#define DINNER 512
#define NHEAD 4
#define DHEAD 128
#define NLAYER 4

__device__ __forceinline__ float wave_sum(float v) {
  #pragma unroll
  for (int off = 32; off > 0; off >>= 1) v += __shfl_xor(v, off, 64);
  return v;
}

// ---------------- embed: h = [x, tf] @ Wp + bp ----------------
__global__ __launch_bounds__(256) void embed_kernel(
    const float* __restrict__ x, const float* __restrict__ tf,
    const float* __restrict__ Wp, const float* __restrict__ bp,
    float* __restrict__ h) {
  int row = blockIdx.x;
  int n = threadIdx.x;
  float xv = x[row];
  const float* t4 = tf + (size_t)row * 4;
  float acc = bp[n] + xv * Wp[n];
  acc += t4[0] * Wp[256 + n];
  acc += t4[1] * Wp[512 + n];
  acc += t4[2] * Wp[768 + n];
  acc += t4[3] * Wp[1024 + n];
  h[(size_t)row * 256 + n] = acc;
}

// ---------------- LayerNorm over 256 ----------------
__global__ __launch_bounds__(256) void ln256_kernel(
    const float* __restrict__ x, const float* __restrict__ g,
    const float* __restrict__ b, float* __restrict__ y) {
  int row = blockIdx.x, tid = threadIdx.x;
  __shared__ float red[4];
  float v = x[(size_t)row * 256 + tid];
  float s = wave_sum(v);
  int wid = tid >> 6, lane = tid & 63;
  if (lane == 0) red[wid] = s;
  __syncthreads();
  float mu = (red[0] + red[1] + red[2] + red[3]) * (1.f / 256.f);
  __syncthreads();
  float d = v - mu;
  float s2 = wave_sum(d * d);
  if (lane == 0) red[wid] = s2;
  __syncthreads();
  float var = (red[0] + red[1] + red[2] + red[3]) * (1.f / 256.f);
  float rs = rsqrtf(var + 1e-5f);
  y[(size_t)row * 256 + tid] = d * rs * g[tid] + b[tid];
}

// ---------------- tiled SGEMM: C[M,N] (+)= A[M,K](lda) @ W[K,N] + bias ----------------
// 128x128 tile, BK=16, 256 threads, 8x8 micro-tile.
__global__ __launch_bounds__(256) void sgemm_kernel(
    const float* __restrict__ A, int lda,
    const float* __restrict__ W, int N, int Kdim,
    const float* __restrict__ bias,
    float* __restrict__ C, int ldc, int accumulate) {
  __shared__ float As[16][132];   // As[k][m]
  __shared__ float Bs[16][132];   // Bs[k][n]
  int tid = threadIdx.x;
  int bm = blockIdx.y * 128, bn = blockIdx.x * 128;
  int ty = tid >> 4, tx = tid & 15;
  float acc[8][8];
  #pragma unroll
  for (int i = 0; i < 8; ++i)
    #pragma unroll
    for (int j = 0; j < 8; ++j) acc[i][j] = 0.f;

  for (int k0 = 0; k0 < Kdim; k0 += 16) {
    // stage A tile (128 rows x 16 k) transposed into As[k][m]
    #pragma unroll
    for (int i = tid; i < 512; i += 256) {
      int r = i >> 2, c4 = i & 3;
      float4 av = *(const float4*)(A + (size_t)(bm + r) * lda + k0 + c4 * 4);
      As[c4 * 4 + 0][r] = av.x;
      As[c4 * 4 + 1][r] = av.y;
      As[c4 * 4 + 2][r] = av.z;
      As[c4 * 4 + 3][r] = av.w;
    }
    // stage B tile (16 k x 128 n)
    #pragma unroll
    for (int i = tid; i < 512; i += 256) {
      int r = i >> 5, c4 = i & 31;
      float4 bv = *(const float4*)(W + (size_t)(k0 + r) * N + bn + c4 * 4);
      *(float4*)&Bs[r][c4 * 4] = bv;
    }
    __syncthreads();
    #pragma unroll 4
    for (int kk = 0; kk < 16; ++kk) {
      float a[8], b[8];
      *(float4*)&a[0] = *(const float4*)&As[kk][ty * 8];
      *(float4*)&a[4] = *(const float4*)&As[kk][ty * 8 + 4];
      *(float4*)&b[0] = *(const float4*)&Bs[kk][tx * 8];
      *(float4*)&b[4] = *(const float4*)&Bs[kk][tx * 8 + 4];
      #pragma unroll
      for (int i = 0; i < 8; ++i)
        #pragma unroll
        for (int j = 0; j < 8; ++j) acc[i][j] += a[i] * b[j];
    }
    __syncthreads();
  }
  #pragma unroll
  for (int i = 0; i < 8; ++i) {
    int r = bm + ty * 8 + i;
    #pragma unroll
    for (int j4 = 0; j4 < 2; ++j4) {
      int cbase = bn + tx * 8 + j4 * 4;
      float* cp = C + (size_t)r * ldc + cbase;
      float4 bb = bias ? *(const float4*)(bias + cbase) : make_float4(0, 0, 0, 0);
      float4 prev = accumulate ? *(const float4*)cp : make_float4(0, 0, 0, 0);
      float4 outv;
      outv.x = acc[i][j4 * 4 + 0] + bb.x + prev.x;
      outv.y = acc[i][j4 * 4 + 1] + bb.y + prev.y;
      outv.z = acc[i][j4 * 4 + 2] + bb.z + prev.z;
      outv.w = acc[i][j4 * 4 + 3] + bb.w + prev.w;
      *(float4*)cp = outv;
    }
  }
}

// ---------------- causal depthwise conv (K=4) + SiLU ----------------
// reads xm = up[..., :512] (row stride 1024), writes xc (row stride 512)
__global__ __launch_bounds__(256) void conv_silu_kernel(
    const float* __restrict__ up, const float* __restrict__ cw,
    const float* __restrict__ cb, float* __restrict__ xc) {
  int idx = blockIdx.x * 256 + threadIdx.x;  // 8192*512
  int c = idx & 511;
  int row = idx >> 9;
  int t = row & (S - 1);
  int bb = row >> 10;
  float acc = cb[c];
  #pragma unroll
  for (int j = 0; j < 4; ++j) {
    int tt = t - 3 + j;
    if (tt >= 0) acc += cw[j * 512 + c] * up[((size_t)(bb * S + tt)) * 1024 + c];
  }
  float sg = 1.f / (1.f + expf(-acc));
  xc[idx] = acc * sg;
}

// ---------------- gates = [q,k,v] @ Wif + bif  (per-row dot of 1536 -> 8) ----------------
__global__ __launch_bounds__(256) void gates_kernel(
    const float* __restrict__ qb, const float* __restrict__ kb,
    const float* __restrict__ vb, const float* __restrict__ Wif,
    const float* __restrict__ bif, float* __restrict__ gates) {
  int row = blockIdx.x, tid = threadIdx.x;
  float part[8] = {0, 0, 0, 0, 0, 0, 0, 0};
  const float* qr = qb + (size_t)row * 512;
  const float* kr = kb + (size_t)row * 512;
  const float* vr = vb + (size_t)row * 512;
  for (int kk = tid; kk < 1536; kk += 256) {
    float xv = (kk < 512) ? qr[kk] : (kk < 1024) ? kr[kk - 512] : vr[kk - 1024];
    const float* wrow = Wif + (size_t)kk * 8;
    #pragma unroll
    for (int j = 0; j < 8; ++j) part[j] += xv * wrow[j];
  }
  __shared__ float red[4][8];
  int wid = tid >> 6, lane = tid & 63;
  #pragma unroll
  for (int j = 0; j < 8; ++j) part[j] = wave_sum(part[j]);
  if (lane == 0) {
    #pragma unroll
    for (int j = 0; j < 8; ++j) red[wid][j] = part[j];
  }
  __syncthreads();
  if (tid < 8) {
    float sv = red[0][tid] + red[1][tid] + red[2][tid] + red[3][tid] + bif[tid];
    gates[(size_t)row * 8 + tid] = sv;
  }
}

// ---------------- per-(b,h) gate scan: F (prefix-sum of logsigmoid(f)),
// g = i - F, M = prefix-max of g, NF = exp(-F - M) ----------------
__global__ __launch_bounds__(1024) void scan_kernel(
    const float* __restrict__ gates, float* __restrict__ gout,
    float* __restrict__ Mout, float* __restrict__ NFout) {
  int bh = blockIdx.x;
  int bb = bh >> 2, hh = bh & 3;
  int t = threadIdx.x;
  __shared__ float buf[1024];
  const float* grow = gates + ((size_t)(bb * S + t)) * 8;
  float ip = grow[hh];
  float fp = grow[4 + hh];
  float lf = fminf(fp, 0.f) - log1pf(expf(-fabsf(fp)));
  buf[t] = lf;
  __syncthreads();
  for (int off = 1; off < 1024; off <<= 1) {
    float prev = (t >= off) ? buf[t - off] : 0.f;
    float cur = buf[t];
    __syncthreads();
    buf[t] = cur + prev;
    __syncthreads();
  }
  float F = buf[t];
  float g = ip - F;
  __syncthreads();
  buf[t] = g;
  __syncthreads();
  for (int off = 1; off < 1024; off <<= 1) {
    float prev = (t >= off) ? buf[t - off] : -3.4e38f;
    float cur = buf[t];
    __syncthreads();
    buf[t] = fmaxf(cur, prev);
    __syncthreads();
  }
  float M = buf[t];
  size_t o = (size_t)bh * S + t;
  gout[o] = g;
  Mout[o] = M;
  NFout[o] = expf(-F - M);
}

// ---------------- mLSTM attention, 64x64 tiles, d halved (LDS 53 KB) ----------------
__global__ __launch_bounds__(256) void attn_kernel(
    const float* __restrict__ q, const float* __restrict__ k,
    const float* __restrict__ v, const float* __restrict__ gbuf,
    const float* __restrict__ Mbuf, const float* __restrict__ NFbuf,
    float* __restrict__ hatt) {
  int bh = blockIdx.y;
  int bb = bh >> 2, hh = bh & 3;
  int tq = blockIdx.x;
  int t0 = tq * 64;
  int tid = threadIdx.x;
  int sy = tid >> 4, sx = tid & 15;
  __shared__ float bufA[64 * 68];
  __shared__ float bufB[64 * 68];
  __shared__ float psb[64 * 68];  // psb[s*68 + t]
  __shared__ float Ml[64], NFl[64], gl[64], rsl[64];
  const float scale = 0.08838834764831845f;  // DH^-0.5

  if (tid < 64) {
    size_t o = (size_t)bh * S + t0 + tid;
    Ml[tid] = Mbuf[o];
    NFl[tid] = NFbuf[o];
  }
  float o0[4][4], o1[4][4];
  #pragma unroll
  for (int i = 0; i < 4; ++i)
    #pragma unroll
    for (int u = 0; u < 4; ++u) { o0[i][u] = 0.f; o1[i][u] = 0.f; }
  float rowsum[4] = {0, 0, 0, 0};
  const float* qbp = q + ((size_t)(bb * S + t0)) * 512 + hh * 128;

  for (int st = 0; st <= tq; ++st) {
    int s0 = st * 64;
    const float* kbp = k + ((size_t)(bb * S + s0)) * 512 + hh * 128;
    const float* vbp = v + ((size_t)(bb * S + s0)) * 512 + hh * 128;
    float acc[4][4];
    #pragma unroll
    for (int i = 0; i < 4; ++i)
      #pragma unroll
      for (int j = 0; j < 4; ++j) acc[i][j] = 0.f;

    #pragma unroll 1
    for (int hd = 0; hd < 2; ++hd) {
      __syncthreads();
      // stage q-half -> bufA[d][t], k-half -> bufB[d][s]
      for (int i = tid; i < 1024; i += 256) {
        int r = i >> 4, c4 = i & 15;
        float4 qv = *(const float4*)(qbp + (size_t)r * 512 + hd * 64 + c4 * 4);
        bufA[(c4 * 4 + 0) * 68 + r] = qv.x;
        bufA[(c4 * 4 + 1) * 68 + r] = qv.y;
        bufA[(c4 * 4 + 2) * 68 + r] = qv.z;
        bufA[(c4 * 4 + 3) * 68 + r] = qv.w;
        float4 kv = *(const float4*)(kbp + (size_t)r * 512 + hd * 64 + c4 * 4);
        bufB[(c4 * 4 + 0) * 68 + r] = kv.x;
        bufB[(c4 * 4 + 1) * 68 + r] = kv.y;
        bufB[(c4 * 4 + 2) * 68 + r] = kv.z;
        bufB[(c4 * 4 + 3) * 68 + r] = kv.w;
      }
      if (hd == 0 && tid < 64) gl[tid] = gbuf[(size_t)bh * S + s0 + tid];
      __syncthreads();
      #pragma unroll 8
      for (int kk = 0; kk < 64; ++kk) {
        float a[4], bv[4];
        *(float4*)a = *(const float4*)&bufA[kk * 68 + sy * 4];
        *(float4*)bv = *(const float4*)&bufB[kk * 68 + sx * 4];
        #pragma unroll
        for (int i = 0; i < 4; ++i)
          #pragma unroll
          for (int j = 0; j < 4; ++j) acc[i][j] += a[i] * bv[j];
      }
    }
    // weights: p = mask * qk*scale*exp(g[s]-M[t]); store transposed psb[s][t]
    #pragma unroll
    for (int j = 0; j < 4; ++j) {
      int s = s0 + sx * 4 + j;
      float gv = gl[sx * 4 + j];
      float w[4];
      #pragma unroll
      for (int i = 0; i < 4; ++i) {
        int t = t0 + sy * 4 + i;
        float val = acc[i][j] * scale * __expf(gv - Ml[sy * 4 + i]);
        w[i] = (s <= t) ? val : 0.f;
      }
      *(float4*)&psb[(sx * 4 + j) * 68 + sy * 4] = make_float4(w[0], w[1], w[2], w[3]);
    }
    __syncthreads();
    // stage v halves into bufA (d 0..63) / bufB (d 64..127), layout [s][d]
    for (int i = tid; i < 1024; i += 256) {
      int r = i >> 4, c4 = i & 15;
      float4 v0 = *(const float4*)(vbp + (size_t)r * 512 + c4 * 4);
      float4 v1 = *(const float4*)(vbp + (size_t)r * 512 + 64 + c4 * 4);
      *(float4*)&bufA[r * 68 + c4 * 4] = v0;
      *(float4*)&bufB[r * 68 + c4 * 4] = v1;
    }
    __syncthreads();
    #pragma unroll 8
    for (int s = 0; s < 64; ++s) {
      float a[4], b0[4], b1[4];
      *(float4*)a = *(const float4*)&psb[s * 68 + sy * 4];
      *(float4*)b0 = *(const float4*)&bufA[s * 68 + sx * 4];
      *(float4*)b1 = *(const float4*)&bufB[s * 68 + sx * 4];
      #pragma unroll
      for (int i = 0; i < 4; ++i) {
        #pragma unroll
        for (int u = 0; u < 4; ++u) {
          o0[i][u] += a[i] * b0[u];
          o1[i][u] += a[i] * b1[u];
        }
      }
      if (sx == 0) {
        #pragma unroll
        for (int i = 0; i < 4; ++i) rowsum[i] += a[i];
      }
    }
  }
  if (sx == 0) {
    #pragma unroll
    for (int i = 0; i < 4; ++i) rsl[sy * 4 + i] = rowsum[i];
  }
  __syncthreads();
  #pragma unroll
  for (int i = 0; i < 4; ++i) {
    int t = t0 + sy * 4 + i;
    float nrm = fmaxf(fabsf(rsl[sy * 4 + i]), NFl[sy * 4 + i]) + 1e-6f;
    float inv = 1.f / nrm;
    float* ob = hatt + ((size_t)(bb * S + t)) * 512 + hh * 128;
    *(float4*)(ob + sx * 4) =
        make_float4(o0[i][0] * inv, o0[i][1] * inv, o0[i][2] * inv, o0[i][3] * inv);
    *(float4*)(ob + 64 + sx * 4) =
        make_float4(o1[i][0] * inv, o1[i][1] * inv, o1[i][2] * inv, o1[i][3] * inv);
  }
}

// ---------------- GroupNorm(128/head) + skip*xc + *silu(z), in-place on hatt ----------------
__global__ __launch_bounds__(512) void gn_kernel(
    float* __restrict__ hatt, const float* __restrict__ gg,
    const float* __restrict__ gb, const float* __restrict__ skip,
    const float* __restrict__ xc, const float* __restrict__ up) {
  int row = blockIdx.x, tid = threadIdx.x;
  int head = tid >> 7;
  __shared__ float red[8];
  float v = hatt[(size_t)row * 512 + tid];
  float s = wave_sum(v);
  int wid = tid >> 6, lane = tid & 63;
  if (lane == 0) red[wid] = s;
  __syncthreads();
  float mu = (red[head * 2] + red[head * 2 + 1]) * (1.f / 128.f);
  __syncthreads();
  float d = v - mu;
  float s2 = wave_sum(d * d);
  if (lane == 0) red[wid] = s2;
  __syncthreads();
  float var = (red[head * 2] + red[head * 2 + 1]) * (1.f / 128.f);
  float rs = rsqrtf(var + 1e-5f);
  float ln = d * rs * gg[tid] + gb[tid];
  float val = ln + skip[tid] * xc[(size_t)row * 512 + tid];
  float z = up[(size_t)row * 1024 + 512 + tid];
  float sg = 1.f / (1.f + expf(-z));
  hatt[(size_t)row * 512 + tid] = val * (z * sg);
}

// ---------------- final LN + head (only last timestep per batch) ----------------
__global__ __launch_bounds__(256) void final_kernel(
    const float* __restrict__ h, const float* __restrict__ g,
    const float* __restrict__ b, const float* __restrict__ Wf,
    const float* __restrict__ bf, float* __restrict__ out) {
  int bb = blockIdx.x, tid = threadIdx.x;
  size_t row = (size_t)(bb * S + S - 1) * 256;
  __shared__ float red[4];
  float v = h[row + tid];
  float s = wave_sum(v);
  int wid = tid >> 6, lane = tid & 63;
  if (lane == 0) red[wid] = s;
  __syncthreads();
  float mu = (red[0] + red[1] + red[2] + red[3]) * (1.f / 256.f);
  __syncthreads();
  float d = v - mu;
  float s2 = wave_sum(d * d);
  if (lane == 0) red[wid] = s2;
  __syncthreads();
  float var = (red[0] + red[1] + red[2] + red[3]) * (1.f / 256.f);
  float rs = rsqrtf(var + 1e-5f);
  float ln = d * rs * g[tid] + b[tid];
  float p = ln * Wf[tid];
  float psum = wave_sum(p);
  __syncthreads();
  if (lane == 0) red[wid] = psum;
  __syncthreads();
  if (tid == 0) out[bb] = red[0] + red[1] + red[2] + red[3] + bf[0];
}

extern "C" void kernel_launch(void* const* d_in, const int* in_sizes, int n_in,
                              void* d_out, int out_size, void* d_ws, size_t ws_size,
                              hipStream_t stream) {
  const float* x      = (const float*)d_in[0];
  const float* tf     = (const float*)d_in[1];
  const float* Wp     = (const float*)d_in[2];
  const float* bp     = (const float*)d_in[3];
  const float* ln_g   = (const float*)d_in[4];
  const float* ln_b   = (const float*)d_in[5];
  const float* Wup    = (const float*)d_in[6];
  const float* bup    = (const float*)d_in[7];
  const float* conv_w = (const float*)d_in[8];
  const float* conv_b = (const float*)d_in[9];
  const float* Wq     = (const float*)d_in[10];
  const float* Wk     = (const float*)d_in[11];
  const float* Wv     = (const float*)d_in[12];
  const float* Wif    = (const float*)d_in[13];
  const float* bif    = (const float*)d_in[14];
  const float* gn_g   = (const float*)d_in[15];
  const float* gn_b   = (const float*)d_in[16];
  const float* skip   = (const float*)d_in[17];
  const float* Wdown  = (const float*)d_in[18];
  const float* bdown  = (const float*)d_in[19];
  const float* lnf_g  = (const float*)d_in[20];
  const float* lnf_b  = (const float*)d_in[21];
  const float* Wf     = (const float*)d_in[22];
  const float* bf     = (const float*)d_in[23];
  float* out = (float*)d_out;

  float* ws = (float*)d_ws;
  float* h     = ws;                  // 2,097,152
  float* hn    = h + 2097152;         // 2,097,152
  float* up    = hn + 2097152;        // 8,388,608
  float* xc    = up + 8388608;        // 4,194,304
  float* qb    = xc + 4194304;        // 4,194,304
  float* kb    = qb + 4194304;        // 4,194,304
  float* vb    = kb + 4194304;        // 4,194,304
  float* hatt  = vb + 4194304;        // 4,194,304
  float* gates = hatt + 4194304;      // 65,536
  float* gbuf  = gates + 65536;       // 32,768
  float* Mbuf  = gbuf + 32768;        // 32,768
  float* NFbuf = Mbuf + 32768;        // 32,768
  // total ~134.9 MB of workspace

  embed_kernel<<<8192, 256, 0, stream>>>(x, tf, Wp, bp, h);
  for (int l = 0; l < NLAYER; ++l) {
    ln256_kernel<<<8192, 256, 0, stream>>>(h, ln_g + l * 256, ln_b + l * 256, hn);
    sgemm_kernel<<<dim3(8, 64), 256, 0, stream>>>(
        hn, 256, Wup + (size_t)l * 256 * 1024, 1024, 256, bup + l * 1024, up, 1024, 0);
    conv_silu_kernel<<<16384, 256, 0, stream>>>(up, conv_w + l * 2048, conv_b + l * 512, xc);
    sgemm_kernel<<<dim3(4, 64), 256, 0, stream>>>(
        xc, 512, Wq + (size_t)l * 512 * 512, 512, 512, nullptr, qb, 512, 0);
    sgemm_kernel<<<dim3(4, 64), 256, 0, stream>>>(
        xc, 512, Wk + (size_t)l * 512 * 512, 512, 512, nullptr, kb, 512, 0);
    sgemm_kernel<<<dim3(4, 64), 256, 0, stream>>>(
        up, 1024, Wv + (size_t)l * 512 * 512, 512, 512, nullptr, vb, 512, 0);
    gates_kernel<<<8192, 256, 0, stream>>>(qb, kb, vb, Wif + (size_t)l * 1536 * 8,
                                           bif + l * 8, gates);
    scan_kernel<<<32, 1024, 0, stream>>>(gates, gbuf, Mbuf, NFbuf);
    attn_kernel<<<dim3(16, 32), 256, 0, stream>>>(qb, kb, vb, gbuf, Mbuf, NFbuf, hatt);
    gn_kernel<<<8192, 512, 0, stream>>>(hatt, gn_g + l * 512, gn_b + l * 512,
                                        skip + l * 512, xc, up);
    sgemm_kernel<<<dim3(2, 64), 256, 0, stream>>>(
        hatt, 512, Wdown + (size_t)l * 512 * 256, 256, 512, bdown + l * 256, h, 256, 1);
  }
  final_kernel<<<8, 256, 0, stream>>>(h, lnf_g, lnf_b, Wf, bf, out);
}

// Round 2
// 1250.930 us; speedup vs baseline: 2.6915x; 2.6915x over previous
//
#include <hip/hip_runtime.h>
#include <hip/hip_bf16.h>
#include <math.h>

#define S 1024
#define NLAYER 4

typedef __bf16 bf16x8 __attribute__((ext_vector_type(8)));
typedef float floatx4 __attribute__((ext_vector_type(4)));

__device__ __forceinline__ float wave_sum(float v) {
  #pragma unroll
  for (int off = 32; off > 0; off >>= 1) v += __shfl_xor(v, off, 64);
  return v;
}

// ---------------- embed: h = [x, tf] @ Wp + bp (fp32) ----------------
__global__ __launch_bounds__(256) void embed_kernel(
    const float* __restrict__ x, const float* __restrict__ tf,
    const float* __restrict__ Wp, const float* __restrict__ bp,
    float* __restrict__ h) {
  int row = blockIdx.x;
  int n = threadIdx.x;
  float xv = x[row];
  const float* t4 = tf + (size_t)row * 4;
  float acc = bp[n] + xv * Wp[n];
  acc += t4[0] * Wp[256 + n];
  acc += t4[1] * Wp[512 + n];
  acc += t4[2] * Wp[768 + n];
  acc += t4[3] * Wp[1024 + n];
  h[(size_t)row * 256 + n] = acc;
}

// ---------------- weight transpose+cast: W[K][N] f32 -> WT[N][K] bf16 ----------------
__global__ __launch_bounds__(256) void wtrans_kernel(
    const float* __restrict__ Wup, const float* __restrict__ Wq,
    const float* __restrict__ Wk, const float* __restrict__ Wv,
    const float* __restrict__ Wdown,
    __bf16* __restrict__ WupT, __bf16* __restrict__ WqT,
    __bf16* __restrict__ WkT, __bf16* __restrict__ WvT,
    __bf16* __restrict__ WdownT) {
  __shared__ float T[32][33];
  int bid = blockIdx.x;
  int layer = bid / 1152, rr = bid % 1152;
  const float* src; __bf16* dst; int K, N, tile;
  if (rr < 256)       { src = Wup   + layer * 262144; dst = WupT   + layer * 262144; K = 256; N = 1024; tile = rr; }
  else if (rr < 512)  { src = Wq    + layer * 262144; dst = WqT    + layer * 262144; K = 512; N = 512;  tile = rr - 256; }
  else if (rr < 768)  { src = Wk    + layer * 262144; dst = WkT    + layer * 262144; K = 512; N = 512;  tile = rr - 512; }
  else if (rr < 1024) { src = Wv    + layer * 262144; dst = WvT    + layer * 262144; K = 512; N = 512;  tile = rr - 768; }
  else                { src = Wdown + layer * 131072; dst = WdownT + layer * 131072; K = 512; N = 256;  tile = rr - 1024; }
  int ntn = N >> 5;
  int tk = tile / ntn, tn = tile % ntn;
  int tid = threadIdx.x;
  int r = tid >> 3, c4 = (tid & 7) * 4;
  float4 v = *(const float4*)(src + (size_t)(tk * 32 + r) * N + tn * 32 + c4);
  T[c4 + 0][r] = v.x; T[c4 + 1][r] = v.y; T[c4 + 2][r] = v.z; T[c4 + 3][r] = v.w;
  __syncthreads();
  __bf16 o[4];
  #pragma unroll
  for (int j = 0; j < 4; ++j) o[j] = (__bf16)T[r][c4 + j];
  *(uint2*)(dst + (size_t)(tn * 32 + r) * K + tk * 32 + c4) = *(uint2*)o;
}

// ---------------- LayerNorm over 256, fp32 in -> bf16 out ----------------
__global__ __launch_bounds__(256) void ln256_kernel(
    const float* __restrict__ x, const float* __restrict__ g,
    const float* __restrict__ b, __bf16* __restrict__ y) {
  int row = blockIdx.x, tid = threadIdx.x;
  __shared__ float red[4];
  float v = x[(size_t)row * 256 + tid];
  float s = wave_sum(v);
  int wid = tid >> 6, lane = tid & 63;
  if (lane == 0) red[wid] = s;
  __syncthreads();
  float mu = (red[0] + red[1] + red[2] + red[3]) * (1.f / 256.f);
  __syncthreads();
  float d = v - mu;
  float s2 = wave_sum(d * d);
  if (lane == 0) red[wid] = s2;
  __syncthreads();
  float var = (red[0] + red[1] + red[2] + red[3]) * (1.f / 256.f);
  float rs = rsqrtf(var + 1e-5f);
  y[(size_t)row * 256 + tid] = (__bf16)(d * rs * g[tid] + b[tid]);
}

// ---------------- bf16 MFMA GEMM: C[M,N] = A[M,K] @ BT[N,K]^T (+bias) ----------------
// 128x128 tile, BK=32, 256 threads (4 waves 2x2), 16x16x32 mfma.
template <int OUT_BF16, int ACC>
__global__ __launch_bounds__(256) void hgemm(
    const __bf16* __restrict__ A, int lda,
    const __bf16* __restrict__ BT, int Kdim,
    const float* __restrict__ bias,
    void* __restrict__ Cout, int ldc) {
  __shared__ __bf16 As[128][40];  // +8 pad: <=2-way LDS conflicts
  __shared__ __bf16 Bs[128][40];
  int tid = threadIdx.x;
  int bn = blockIdx.x * 128, bm = blockIdx.y * 128;
  int wid = tid >> 6, lane = tid & 63;
  int wr = wid >> 1, wc = wid & 1;
  int lg = lane >> 4, li = lane & 15;
  floatx4 acc[4][4];
  #pragma unroll
  for (int i = 0; i < 4; ++i)
    #pragma unroll
    for (int j = 0; j < 4; ++j) acc[i][j] = (floatx4)(0.f);

  int arow = tid >> 2, aseg = tid & 3;
  for (int k0 = 0; k0 < Kdim; k0 += 32) {
    __syncthreads();
    *(bf16x8*)&As[arow][aseg * 8] =
        *(const bf16x8*)(A + (size_t)(bm + arow) * lda + k0 + aseg * 8);
    *(bf16x8*)&As[arow + 64][aseg * 8] =
        *(const bf16x8*)(A + (size_t)(bm + arow + 64) * lda + k0 + aseg * 8);
    *(bf16x8*)&Bs[arow][aseg * 8] =
        *(const bf16x8*)(BT + (size_t)(bn + arow) * Kdim + k0 + aseg * 8);
    *(bf16x8*)&Bs[arow + 64][aseg * 8] =
        *(const bf16x8*)(BT + (size_t)(bn + arow + 64) * Kdim + k0 + aseg * 8);
    __syncthreads();
    bf16x8 af[4], bfr[4];
    #pragma unroll
    for (int mi = 0; mi < 4; ++mi)
      af[mi] = *(const bf16x8*)&As[wr * 64 + mi * 16 + li][lg * 8];
    #pragma unroll
    for (int ni = 0; ni < 4; ++ni)
      bfr[ni] = *(const bf16x8*)&Bs[wc * 64 + ni * 16 + li][lg * 8];
    #pragma unroll
    for (int mi = 0; mi < 4; ++mi)
      #pragma unroll
      for (int ni = 0; ni < 4; ++ni)
        acc[mi][ni] = __builtin_amdgcn_mfma_f32_16x16x32_bf16(af[mi], bfr[ni], acc[mi][ni], 0, 0, 0);
  }
  #pragma unroll
  for (int mi = 0; mi < 4; ++mi) {
    int row = bm + wr * 64 + mi * 16 + lg * 4;
    #pragma unroll
    for (int ni = 0; ni < 4; ++ni) {
      int col = bn + wc * 64 + ni * 16 + li;
      float bz = bias ? bias[col] : 0.f;
      if (OUT_BF16) {
        __bf16* C = (__bf16*)Cout;
        #pragma unroll
        for (int r = 0; r < 4; ++r)
          C[(size_t)(row + r) * ldc + col] = (__bf16)(acc[mi][ni][r] + bz);
      } else {
        float* C = (float*)Cout;
        #pragma unroll
        for (int r = 0; r < 4; ++r) {
          float v = acc[mi][ni][r] + bz;
          if (ACC) v += C[(size_t)(row + r) * ldc + col];
          C[(size_t)(row + r) * ldc + col] = v;
        }
      }
    }
  }
}

// ---------------- causal depthwise conv (K=4) + SiLU, bf16 in/out ----------------
__global__ __launch_bounds__(256) void conv_silu_kernel(
    const __bf16* __restrict__ up, const float* __restrict__ cw,
    const float* __restrict__ cb, __bf16* __restrict__ xc) {
  int idx = blockIdx.x * 256 + threadIdx.x;  // 8192*512
  int c = idx & 511;
  int row = idx >> 9;
  int t = row & (S - 1);
  int bb = row >> 10;
  float acc = cb[c];
  #pragma unroll
  for (int j = 0; j < 4; ++j) {
    int tt = t - 3 + j;
    if (tt >= 0) acc += cw[j * 512 + c] * (float)up[((size_t)(bb * S + tt)) * 1024 + c];
  }
  float sg = 1.f / (1.f + expf(-acc));
  xc[idx] = (__bf16)(acc * sg);
}

// ---------------- gates = [q,k,v] @ Wif + bif ----------------
__global__ __launch_bounds__(256) void gates_kernel(
    const __bf16* __restrict__ qb, const __bf16* __restrict__ kb,
    const __bf16* __restrict__ vb, const float* __restrict__ Wif,
    const float* __restrict__ bif, float* __restrict__ gates) {
  int row = blockIdx.x, tid = threadIdx.x;
  float part[8] = {0, 0, 0, 0, 0, 0, 0, 0};
  const __bf16* qr = qb + (size_t)row * 512;
  const __bf16* kr = kb + (size_t)row * 512;
  const __bf16* vr = vb + (size_t)row * 512;
  for (int kk = tid; kk < 1536; kk += 256) {
    float xv = (kk < 512) ? (float)qr[kk] : (kk < 1024) ? (float)kr[kk - 512] : (float)vr[kk - 1024];
    const float* wrow = Wif + (size_t)kk * 8;
    #pragma unroll
    for (int j = 0; j < 8; ++j) part[j] += xv * wrow[j];
  }
  __shared__ float red[4][8];
  int wid = tid >> 6, lane = tid & 63;
  #pragma unroll
  for (int j = 0; j < 8; ++j) part[j] = wave_sum(part[j]);
  if (lane == 0) {
    #pragma unroll
    for (int j = 0; j < 8; ++j) red[wid][j] = part[j];
  }
  __syncthreads();
  if (tid < 8) {
    float sv = red[0][tid] + red[1][tid] + red[2][tid] + red[3][tid] + bif[tid];
    gates[(size_t)row * 8 + tid] = sv;
  }
}

// ---------------- per-(b,h) gate scan ----------------
__global__ __launch_bounds__(1024) void scan_kernel(
    const float* __restrict__ gates, float* __restrict__ gout,
    float* __restrict__ Mout, float* __restrict__ NFout) {
  int bh = blockIdx.x;
  int bb = bh >> 2, hh = bh & 3;
  int t = threadIdx.x;
  __shared__ float buf[1024];
  const float* grow = gates + ((size_t)(bb * S + t)) * 8;
  float ip = grow[hh];
  float fp = grow[4 + hh];
  float lf = fminf(fp, 0.f) - log1pf(expf(-fabsf(fp)));
  buf[t] = lf;
  __syncthreads();
  for (int off = 1; off < 1024; off <<= 1) {
    float prev = (t >= off) ? buf[t - off] : 0.f;
    float cur = buf[t];
    __syncthreads();
    buf[t] = cur + prev;
    __syncthreads();
  }
  float F = buf[t];
  float g = ip - F;
  __syncthreads();
  buf[t] = g;
  __syncthreads();
  for (int off = 1; off < 1024; off <<= 1) {
    float prev = (t >= off) ? buf[t - off] : -3.4e38f;
    float cur = buf[t];
    __syncthreads();
    buf[t] = fmaxf(cur, prev);
    __syncthreads();
  }
  float M = buf[t];
  size_t o = (size_t)bh * S + t;
  gout[o] = g;
  Mout[o] = M;
  NFout[o] = expf(-F - M);
}

// ---------------- V transpose: vb[B*S][512] bf16 -> vT[bh][128][1024] bf16 ----------------
__global__ __launch_bounds__(256) void vtrans_kernel(
    const __bf16* __restrict__ vb, __bf16* __restrict__ vT) {
  __shared__ __bf16 T[64][72];
  int b = blockIdx.x;  // 1024
  int bh = b >> 5;
  int tt = (b >> 1) & 15;
  int dt = b & 1;
  int bb = bh >> 2, hh = bh & 3;
  int tid = threadIdx.x;
  int r = tid >> 3, c8 = (tid & 7) * 8;
  #pragma unroll
  for (int half = 0; half < 2; ++half) {
    int trow = r + half * 32;
    bf16x8 v = *(const bf16x8*)(vb + ((size_t)(bb * S + tt * 64 + trow)) * 512 + hh * 128 + dt * 64 + c8);
    #pragma unroll
    for (int j = 0; j < 8; ++j) T[c8 + j][trow] = v[j];
  }
  __syncthreads();
  #pragma unroll
  for (int half = 0; half < 2; ++half) {
    int drow = r + half * 32;
    bf16x8 o;
    #pragma unroll
    for (int j = 0; j < 8; ++j) o[j] = T[drow][c8 + j];
    *(bf16x8*)(vT + ((size_t)(bh * 128 + dt * 64 + drow)) * 1024 + tt * 64 + c8) = o;
  }
}

// ---------------- MFMA mLSTM attention ----------------
// block = (tq, bh), 256 threads = 4 waves; wave w owns t-rows [tq*64+w*16, +16)
__global__ __launch_bounds__(256) void attn_kernel(
    const __bf16* __restrict__ qb, const __bf16* __restrict__ kb,
    const __bf16* __restrict__ vT, const float* __restrict__ gbuf,
    const float* __restrict__ Mbuf, const float* __restrict__ NFbuf,
    float* __restrict__ hatt) {
  __shared__ __bf16 plds[4][16][72];
  int tq = blockIdx.x, bh = blockIdx.y;
  int bb = bh >> 2, hh = bh & 3;
  int tid = threadIdx.x;
  int wv = tid >> 6, lane = tid & 63;
  int lg = lane >> 4, li = lane & 15;
  int tb = tq * 64 + wv * 16;
  const float scale = 0.08838834764831845f;

  // Q A-frags (held whole kernel)
  bf16x8 aq[4];
  const __bf16* qp = qb + ((size_t)(bb * S + tb + li)) * 512 + hh * 128 + lg * 8;
  #pragma unroll
  for (int cd = 0; cd < 4; ++cd) aq[cd] = *(const bf16x8*)(qp + cd * 32);

  float ml[4], nf[4];
  #pragma unroll
  for (int r = 0; r < 4; ++r) {
    ml[r] = Mbuf[(size_t)bh * S + tb + lg * 4 + r];
    nf[r] = NFbuf[(size_t)bh * S + tb + lg * 4 + r];
  }

  floatx4 oacc[8];
  #pragma unroll
  for (int df = 0; df < 8; ++df) oacc[df] = (floatx4)(0.f);
  float rs[4] = {0, 0, 0, 0};

  for (int st = 0; st <= tq; ++st) {
    int s0 = st * 64;
    // ---- QK^T + weighting ----
    #pragma unroll
    for (int ns = 0; ns < 4; ++ns) {
      const __bf16* kp = kb + ((size_t)(bb * S + s0 + ns * 16 + li)) * 512 + hh * 128 + lg * 8;
      bf16x8 bk0 = *(const bf16x8*)(kp);
      bf16x8 bk1 = *(const bf16x8*)(kp + 32);
      bf16x8 bk2 = *(const bf16x8*)(kp + 64);
      bf16x8 bk3 = *(const bf16x8*)(kp + 96);
      floatx4 pa = (floatx4)(0.f);
      pa = __builtin_amdgcn_mfma_f32_16x16x32_bf16(aq[0], bk0, pa, 0, 0, 0);
      pa = __builtin_amdgcn_mfma_f32_16x16x32_bf16(aq[1], bk1, pa, 0, 0, 0);
      pa = __builtin_amdgcn_mfma_f32_16x16x32_bf16(aq[2], bk2, pa, 0, 0, 0);
      pa = __builtin_amdgcn_mfma_f32_16x16x32_bf16(aq[3], bk3, pa, 0, 0, 0);
      int s = s0 + ns * 16 + li;
      float gv = gbuf[(size_t)bh * S + s];
      #pragma unroll
      for (int r = 0; r < 4; ++r) {
        int t = tb + lg * 4 + r;
        float val = pa[r] * scale * __expf(gv - ml[r]);
        float w = (s <= t) ? val : 0.f;
        rs[r] += w;
        plds[wv][lg * 4 + r][ns * 16 + li] = (__bf16)w;
      }
    }
    __syncthreads();
    // ---- PV ----
    bf16x8 ap0 = *(const bf16x8*)&plds[wv][li][lg * 8];
    bf16x8 ap1 = *(const bf16x8*)&plds[wv][li][32 + lg * 8];
    #pragma unroll
    for (int df = 0; df < 8; ++df) {
      const __bf16* vp = vT + ((size_t)(bh * 128 + df * 16 + li)) * S + s0 + lg * 8;
      bf16x8 bv0 = *(const bf16x8*)(vp);
      bf16x8 bv1 = *(const bf16x8*)(vp + 32);
      oacc[df] = __builtin_amdgcn_mfma_f32_16x16x32_bf16(ap0, bv0, oacc[df], 0, 0, 0);
      oacc[df] = __builtin_amdgcn_mfma_f32_16x16x32_bf16(ap1, bv1, oacc[df], 0, 0, 0);
    }
    __syncthreads();
  }
  // reduce row sums across the 16 col-lanes (bits 0..3)
  #pragma unroll
  for (int r = 0; r < 4; ++r) {
    float v = rs[r];
    v += __shfl_xor(v, 1, 64);
    v += __shfl_xor(v, 2, 64);
    v += __shfl_xor(v, 4, 64);
    v += __shfl_xor(v, 8, 64);
    rs[r] = v;
  }
  #pragma unroll
  for (int r = 0; r < 4; ++r) {
    float nrm = fmaxf(fabsf(rs[r]), nf[r]) + 1e-6f;
    float inv = 1.f / nrm;
    float* ob = hatt + ((size_t)(bb * S + tb + lg * 4 + r)) * 512 + hh * 128 + li;
    #pragma unroll
    for (int df = 0; df < 8; ++df) ob[df * 16] = oacc[df][r] * inv;
  }
}

// ---------------- GroupNorm + skip*xc + *silu(z): hatt f32 -> hd bf16 ----------------
__global__ __launch_bounds__(512) void gn_kernel(
    const float* __restrict__ hatt, const float* __restrict__ gg,
    const float* __restrict__ gb, const float* __restrict__ skip,
    const __bf16* __restrict__ xc, const __bf16* __restrict__ up,
    __bf16* __restrict__ hd) {
  int row = blockIdx.x, tid = threadIdx.x;
  int head = tid >> 7;
  __shared__ float red[8];
  float v = hatt[(size_t)row * 512 + tid];
  float s = wave_sum(v);
  int wid = tid >> 6, lane = tid & 63;
  if (lane == 0) red[wid] = s;
  __syncthreads();
  float mu = (red[head * 2] + red[head * 2 + 1]) * (1.f / 128.f);
  __syncthreads();
  float d = v - mu;
  float s2 = wave_sum(d * d);
  if (lane == 0) red[wid] = s2;
  __syncthreads();
  float var = (red[head * 2] + red[head * 2 + 1]) * (1.f / 128.f);
  float rsq = rsqrtf(var + 1e-5f);
  float ln = d * rsq * gg[tid] + gb[tid];
  float val = ln + skip[tid] * (float)xc[(size_t)row * 512 + tid];
  float z = (float)up[(size_t)row * 1024 + 512 + tid];
  float sg = 1.f / (1.f + expf(-z));
  hd[(size_t)row * 512 + tid] = (__bf16)(val * (z * sg));
}

// ---------------- final LN + head ----------------
__global__ __launch_bounds__(256) void final_kernel(
    const float* __restrict__ h, const float* __restrict__ g,
    const float* __restrict__ b, const float* __restrict__ Wf,
    const float* __restrict__ bf, float* __restrict__ out) {
  int bb = blockIdx.x, tid = threadIdx.x;
  size_t row = (size_t)(bb * S + S - 1) * 256;
  __shared__ float red[4];
  float v = h[row + tid];
  float s = wave_sum(v);
  int wid = tid >> 6, lane = tid & 63;
  if (lane == 0) red[wid] = s;
  __syncthreads();
  float mu = (red[0] + red[1] + red[2] + red[3]) * (1.f / 256.f);
  __syncthreads();
  float d = v - mu;
  float s2 = wave_sum(d * d);
  if (lane == 0) red[wid] = s2;
  __syncthreads();
  float var = (red[0] + red[1] + red[2] + red[3]) * (1.f / 256.f);
  float rs = rsqrtf(var + 1e-5f);
  float ln = d * rs * g[tid] + b[tid];
  float p = ln * Wf[tid];
  float psum = wave_sum(p);
  __syncthreads();
  if (lane == 0) red[wid] = psum;
  __syncthreads();
  if (tid == 0) out[bb] = red[0] + red[1] + red[2] + red[3] + bf[0];
}

extern "C" void kernel_launch(void* const* d_in, const int* in_sizes, int n_in,
                              void* d_out, int out_size, void* d_ws, size_t ws_size,
                              hipStream_t stream) {
  const float* x      = (const float*)d_in[0];
  const float* tf     = (const float*)d_in[1];
  const float* Wp     = (const float*)d_in[2];
  const float* bp     = (const float*)d_in[3];
  const float* ln_g   = (const float*)d_in[4];
  const float* ln_b   = (const float*)d_in[5];
  const float* Wup    = (const float*)d_in[6];
  const float* bup    = (const float*)d_in[7];
  const float* conv_w = (const float*)d_in[8];
  const float* conv_b = (const float*)d_in[9];
  const float* Wq     = (const float*)d_in[10];
  const float* Wk     = (const float*)d_in[11];
  const float* Wv     = (const float*)d_in[12];
  const float* Wif    = (const float*)d_in[13];
  const float* bif    = (const float*)d_in[14];
  const float* gn_g   = (const float*)d_in[15];
  const float* gn_b   = (const float*)d_in[16];
  const float* skip   = (const float*)d_in[17];
  const float* Wdown  = (const float*)d_in[18];
  const float* bdown  = (const float*)d_in[19];
  const float* lnf_g  = (const float*)d_in[20];
  const float* lnf_b  = (const float*)d_in[21];
  const float* Wf     = (const float*)d_in[22];
  const float* bf     = (const float*)d_in[23];
  float* out = (float*)d_out;

  float* h     = (float*)d_ws;            // 2,097,152 f32
  float* hatt  = h + 2097152;             // 4,194,304 f32
  float* gates = hatt + 4194304;          // 65,536 f32
  float* gbuf  = gates + 65536;           // 32,768
  float* Mbuf  = gbuf + 32768;            // 32,768
  float* NFbuf = Mbuf + 32768;            // 32,768
  __bf16* hn   = (__bf16*)(NFbuf + 32768);  // 2,097,152 bf16
  __bf16* up   = hn + 2097152;            // 8,388,608
  __bf16* xc   = up + 8388608;            // 4,194,304
  __bf16* qbuf = xc + 4194304;            // 4,194,304
  __bf16* kbuf = qbuf + 4194304;          // 4,194,304
  __bf16* vbuf = kbuf + 4194304;          // 4,194,304
  __bf16* vT   = vbuf + 4194304;          // 4,194,304
  __bf16* hd   = vT + 4194304;            // 4,194,304
  __bf16* WupT   = hd + 4194304;          // 1,048,576
  __bf16* WqT    = WupT + 1048576;        // 1,048,576
  __bf16* WkT    = WqT + 1048576;         // 1,048,576
  __bf16* WvT    = WkT + 1048576;         // 1,048,576
  __bf16* WdownT = WvT + 1048576;         // 524,288
  // ~106 MB total

  wtrans_kernel<<<4608, 256, 0, stream>>>(Wup, Wq, Wk, Wv, Wdown,
                                          WupT, WqT, WkT, WvT, WdownT);
  embed_kernel<<<8192, 256, 0, stream>>>(x, tf, Wp, bp, h);
  for (int l = 0; l < NLAYER; ++l) {
    ln256_kernel<<<8192, 256, 0, stream>>>(h, ln_g + l * 256, ln_b + l * 256, hn);
    hgemm<1, 0><<<dim3(8, 64), 256, 0, stream>>>(
        hn, 256, WupT + (size_t)l * 262144, 256, bup + l * 1024, up, 1024);
    conv_silu_kernel<<<16384, 256, 0, stream>>>(up, conv_w + l * 2048, conv_b + l * 512, xc);
    hgemm<1, 0><<<dim3(4, 64), 256, 0, stream>>>(
        xc, 512, WqT + (size_t)l * 262144, 512, nullptr, qbuf, 512);
    hgemm<1, 0><<<dim3(4, 64), 256, 0, stream>>>(
        xc, 512, WkT + (size_t)l * 262144, 512, nullptr, kbuf, 512);
    hgemm<1, 0><<<dim3(4, 64), 256, 0, stream>>>(
        up, 1024, WvT + (size_t)l * 262144, 512, nullptr, vbuf, 512);
    gates_kernel<<<8192, 256, 0, stream>>>(qbuf, kbuf, vbuf, Wif + (size_t)l * 1536 * 8,
                                           bif + l * 8, gates);
    scan_kernel<<<32, 1024, 0, stream>>>(gates, gbuf, Mbuf, NFbuf);
    vtrans_kernel<<<1024, 256, 0, stream>>>(vbuf, vT);
    attn_kernel<<<dim3(16, 32), 256, 0, stream>>>(qbuf, kbuf, vT, gbuf, Mbuf, NFbuf, hatt);
    gn_kernel<<<8192, 512, 0, stream>>>(hatt, gn_g + l * 512, gn_b + l * 512,
                                        skip + l * 512, xc, up, hd);
    hgemm<0, 1><<<dim3(2, 64), 256, 0, stream>>>(
        hd, 512, WdownT + (size_t)l * 131072, 512, bdown + l * 256, h, 256);
  }
  final_kernel<<<8, 256, 0, stream>>>(h, lnf_g, lnf_b, Wf, bf, out);
}

// Round 4
// 908.707 us; speedup vs baseline: 3.7051x; 1.3766x over previous
//
#include <hip/hip_runtime.h>
#include <hip/hip_bf16.h>
#include <math.h>

#define S 1024
#define NLAYER 4

typedef __bf16 bf16x8 __attribute__((ext_vector_type(8)));
typedef float floatx4 __attribute__((ext_vector_type(4)));

__device__ __forceinline__ float wave_sum(float v) {
  #pragma unroll
  for (int off = 32; off > 0; off >>= 1) v += __shfl_xor(v, off, 64);
  return v;
}

// ---------------- embed: h = [x, tf] @ Wp + bp (fp32) ----------------
__global__ __launch_bounds__(256) void embed_kernel(
    const float* __restrict__ x, const float* __restrict__ tf,
    const float* __restrict__ Wp, const float* __restrict__ bp,
    float* __restrict__ h) {
  int row = blockIdx.x;
  int n = threadIdx.x;
  float xv = x[row];
  const float* t4 = tf + (size_t)row * 4;
  float acc = bp[n] + xv * Wp[n];
  acc += t4[0] * Wp[256 + n];
  acc += t4[1] * Wp[512 + n];
  acc += t4[2] * Wp[768 + n];
  acc += t4[3] * Wp[1024 + n];
  h[(size_t)row * 256 + n] = acc;
}

// ---------------- weight transpose+cast: W[K][N] f32 -> WT[N][K] bf16 ----------------
__global__ __launch_bounds__(256) void wtrans_kernel(
    const float* __restrict__ Wup, const float* __restrict__ Wq,
    const float* __restrict__ Wk, const float* __restrict__ Wv,
    const float* __restrict__ Wdown,
    __bf16* __restrict__ WupT, __bf16* __restrict__ WqT,
    __bf16* __restrict__ WkT, __bf16* __restrict__ WvT,
    __bf16* __restrict__ WdownT) {
  __shared__ float T[32][33];
  int bid = blockIdx.x;
  int layer = bid / 1152, rr = bid % 1152;
  const float* src; __bf16* dst; int K, N, tile;
  if (rr < 256)       { src = Wup   + layer * 262144; dst = WupT   + layer * 262144; K = 256; N = 1024; tile = rr; }
  else if (rr < 512)  { src = Wq    + layer * 262144; dst = WqT    + layer * 262144; K = 512; N = 512;  tile = rr - 256; }
  else if (rr < 768)  { src = Wk    + layer * 262144; dst = WkT    + layer * 262144; K = 512; N = 512;  tile = rr - 512; }
  else if (rr < 1024) { src = Wv    + layer * 262144; dst = WvT    + layer * 262144; K = 512; N = 512;  tile = rr - 768; }
  else                { src = Wdown + layer * 131072; dst = WdownT + layer * 131072; K = 512; N = 256;  tile = rr - 1024; }
  int ntn = N >> 5;
  int tk = tile / ntn, tn = tile % ntn;
  int tid = threadIdx.x;
  int r = tid >> 3, c4 = (tid & 7) * 4;
  float4 v = *(const float4*)(src + (size_t)(tk * 32 + r) * N + tn * 32 + c4);
  T[c4 + 0][r] = v.x; T[c4 + 1][r] = v.y; T[c4 + 2][r] = v.z; T[c4 + 3][r] = v.w;
  __syncthreads();
  __bf16 o[4];
  #pragma unroll
  for (int j = 0; j < 4; ++j) o[j] = (__bf16)T[r][c4 + j];
  *(uint2*)(dst + (size_t)(tn * 32 + r) * K + tk * 32 + c4) = *(uint2*)o;
}

// ---------------- LayerNorm over 256, fp32 in -> bf16 out ----------------
__global__ __launch_bounds__(256) void ln256_kernel(
    const float* __restrict__ x, const float* __restrict__ g,
    const float* __restrict__ b, __bf16* __restrict__ y) {
  int row = blockIdx.x, tid = threadIdx.x;
  __shared__ float red[4];
  float v = x[(size_t)row * 256 + tid];
  float s = wave_sum(v);
  int wid = tid >> 6, lane = tid & 63;
  if (lane == 0) red[wid] = s;
  __syncthreads();
  float mu = (red[0] + red[1] + red[2] + red[3]) * (1.f / 256.f);
  __syncthreads();
  float d = v - mu;
  float s2 = wave_sum(d * d);
  if (lane == 0) red[wid] = s2;
  __syncthreads();
  float var = (red[0] + red[1] + red[2] + red[3]) * (1.f / 256.f);
  float rs = rsqrtf(var + 1e-5f);
  y[(size_t)row * 256 + tid] = (__bf16)(d * rs * g[tid] + b[tid]);
}

// ---------------- bf16 MFMA GEMM: C[M,N] = A[M,K] @ BT[N,K]^T (+bias) ----------------
template <int OUT_BF16, int ACC>
__global__ __launch_bounds__(256) void hgemm(
    const __bf16* __restrict__ A, int lda,
    const __bf16* __restrict__ BT, int Kdim,
    const float* __restrict__ bias,
    void* __restrict__ Cout, int ldc) {
  __shared__ __bf16 As[128][40];
  __shared__ __bf16 Bs[128][40];
  int tid = threadIdx.x;
  int bn = blockIdx.x * 128, bm = blockIdx.y * 128;
  int wid = tid >> 6, lane = tid & 63;
  int wr = wid >> 1, wc = wid & 1;
  int lg = lane >> 4, li = lane & 15;
  floatx4 acc[4][4];
  #pragma unroll
  for (int i = 0; i < 4; ++i)
    #pragma unroll
    for (int j = 0; j < 4; ++j) acc[i][j] = (floatx4)(0.f);

  int arow = tid >> 2, aseg = tid & 3;
  for (int k0 = 0; k0 < Kdim; k0 += 32) {
    __syncthreads();
    *(bf16x8*)&As[arow][aseg * 8] =
        *(const bf16x8*)(A + (size_t)(bm + arow) * lda + k0 + aseg * 8);
    *(bf16x8*)&As[arow + 64][aseg * 8] =
        *(const bf16x8*)(A + (size_t)(bm + arow + 64) * lda + k0 + aseg * 8);
    *(bf16x8*)&Bs[arow][aseg * 8] =
        *(const bf16x8*)(BT + (size_t)(bn + arow) * Kdim + k0 + aseg * 8);
    *(bf16x8*)&Bs[arow + 64][aseg * 8] =
        *(const bf16x8*)(BT + (size_t)(bn + arow + 64) * Kdim + k0 + aseg * 8);
    __syncthreads();
    bf16x8 af[4], bfr[4];
    #pragma unroll
    for (int mi = 0; mi < 4; ++mi)
      af[mi] = *(const bf16x8*)&As[wr * 64 + mi * 16 + li][lg * 8];
    #pragma unroll
    for (int ni = 0; ni < 4; ++ni)
      bfr[ni] = *(const bf16x8*)&Bs[wc * 64 + ni * 16 + li][lg * 8];
    #pragma unroll
    for (int mi = 0; mi < 4; ++mi)
      #pragma unroll
      for (int ni = 0; ni < 4; ++ni)
        acc[mi][ni] = __builtin_amdgcn_mfma_f32_16x16x32_bf16(af[mi], bfr[ni], acc[mi][ni], 0, 0, 0);
  }
  #pragma unroll
  for (int mi = 0; mi < 4; ++mi) {
    int row = bm + wr * 64 + mi * 16 + lg * 4;
    #pragma unroll
    for (int ni = 0; ni < 4; ++ni) {
      int col = bn + wc * 64 + ni * 16 + li;
      float bz = bias ? bias[col] : 0.f;
      if (OUT_BF16) {
        __bf16* C = (__bf16*)Cout;
        #pragma unroll
        for (int r = 0; r < 4; ++r)
          C[(size_t)(row + r) * ldc + col] = (__bf16)(acc[mi][ni][r] + bz);
      } else {
        float* C = (float*)Cout;
        #pragma unroll
        for (int r = 0; r < 4; ++r) {
          float v = acc[mi][ni][r] + bz;
          if (ACC) v += C[(size_t)(row + r) * ldc + col];
          C[(size_t)(row + r) * ldc + col] = v;
        }
      }
    }
  }
}

// ---------------- causal depthwise conv (K=4) + SiLU, bf16 in/out ----------------
__global__ __launch_bounds__(256) void conv_silu_kernel(
    const __bf16* __restrict__ up, const float* __restrict__ cw,
    const float* __restrict__ cb, __bf16* __restrict__ xc) {
  int idx = blockIdx.x * 256 + threadIdx.x;  // 8192*512
  int c = idx & 511;
  int row = idx >> 9;
  int t = row & (S - 1);
  int bb = row >> 10;
  float acc = cb[c];
  #pragma unroll
  for (int j = 0; j < 4; ++j) {
    int tt = t - 3 + j;
    if (tt >= 0) acc += cw[j * 512 + c] * (float)up[((size_t)(bb * S + tt)) * 1024 + c];
  }
  float sg = 1.f / (1.f + expf(-acc));
  xc[idx] = (__bf16)(acc * sg);
}

// ---------------- gates = [q,k,v] @ Wif + bif ----------------
__global__ __launch_bounds__(256) void gates_kernel(
    const __bf16* __restrict__ qb, const __bf16* __restrict__ kb,
    const __bf16* __restrict__ vb, const float* __restrict__ Wif,
    const float* __restrict__ bif, float* __restrict__ gates) {
  int row = blockIdx.x, tid = threadIdx.x;
  float part[8] = {0, 0, 0, 0, 0, 0, 0, 0};
  const __bf16* qr = qb + (size_t)row * 512;
  const __bf16* kr = kb + (size_t)row * 512;
  const __bf16* vr = vb + (size_t)row * 512;
  for (int kk = tid; kk < 1536; kk += 256) {
    float xv = (kk < 512) ? (float)qr[kk] : (kk < 1024) ? (float)kr[kk - 512] : (float)vr[kk - 1024];
    const float* wrow = Wif + (size_t)kk * 8;
    #pragma unroll
    for (int j = 0; j < 8; ++j) part[j] += xv * wrow[j];
  }
  __shared__ float red[4][8];
  int wid = tid >> 6, lane = tid & 63;
  #pragma unroll
  for (int j = 0; j < 8; ++j) part[j] = wave_sum(part[j]);
  if (lane == 0) {
    #pragma unroll
    for (int j = 0; j < 8; ++j) red[wid][j] = part[j];
  }
  __syncthreads();
  if (tid < 8) {
    float sv = red[0][tid] + red[1][tid] + red[2][tid] + red[3][tid] + bif[tid];
    gates[(size_t)row * 8 + tid] = sv;
  }
}

// ---------------- per-(b,h) gate scan ----------------
__global__ __launch_bounds__(1024) void scan_kernel(
    const float* __restrict__ gates, float* __restrict__ gout,
    float* __restrict__ Mout, float* __restrict__ NFout) {
  int bh = blockIdx.x;
  int bb = bh >> 2, hh = bh & 3;
  int t = threadIdx.x;
  __shared__ float buf[1024];
  const float* grow = gates + ((size_t)(bb * S + t)) * 8;
  float ip = grow[hh];
  float fp = grow[4 + hh];
  float lf = fminf(fp, 0.f) - log1pf(expf(-fabsf(fp)));
  buf[t] = lf;
  __syncthreads();
  for (int off = 1; off < 1024; off <<= 1) {
    float prev = (t >= off) ? buf[t - off] : 0.f;
    float cur = buf[t];
    __syncthreads();
    buf[t] = cur + prev;
    __syncthreads();
  }
  float F = buf[t];
  float g = ip - F;
  __syncthreads();
  buf[t] = g;
  __syncthreads();
  for (int off = 1; off < 1024; off <<= 1) {
    float prev = (t >= off) ? buf[t - off] : -3.4e38f;
    float cur = buf[t];
    __syncthreads();
    buf[t] = fmaxf(cur, prev);
    __syncthreads();
  }
  float M = buf[t];
  size_t o = (size_t)bh * S + t;
  gout[o] = g;
  Mout[o] = M;
  NFout[o] = expf(-F - M);
}

// ---------------- V transpose: vb[B*S][512] bf16 -> vT[bh][128][1024] bf16 ----------------
__global__ __launch_bounds__(256) void vtrans_kernel(
    const __bf16* __restrict__ vb, __bf16* __restrict__ vT) {
  __shared__ __bf16 T[64][72];
  int b = blockIdx.x;  // 1024
  int bh = b >> 5;
  int tt = (b >> 1) & 15;
  int dt = b & 1;
  int bb = bh >> 2, hh = bh & 3;
  int tid = threadIdx.x;
  int r = tid >> 3, c8 = (tid & 7) * 8;
  #pragma unroll
  for (int half = 0; half < 2; ++half) {
    int trow = r + half * 32;
    bf16x8 v = *(const bf16x8*)(vb + ((size_t)(bb * S + tt * 64 + trow)) * 512 + hh * 128 + dt * 64 + c8);
    #pragma unroll
    for (int j = 0; j < 8; ++j) T[c8 + j][trow] = v[j];
  }
  __syncthreads();
  #pragma unroll
  for (int half = 0; half < 2; ++half) {
    int drow = r + half * 32;
    bf16x8 o;
    #pragma unroll
    for (int j = 0; j < 8; ++j) o[j] = T[drow][c8 + j];
    *(bf16x8*)(vT + ((size_t)(bh * 128 + dt * 64 + drow)) * 1024 + tt * 64 + c8) = o;
  }
}

// ---------------- MFMA mLSTM attention, paired q-tiles + LDS staging ----------------
// grid (8, 32): block px handles q-tiles tqA=px, tqB=15-px (17 tile-computes each).
// 4 waves; wave wv owns t-rows [tq*64+wv*16, +16) of BOTH tiles.
__global__ __launch_bounds__(256, 1) void attn_kernel(
    const __bf16* __restrict__ qb, const __bf16* __restrict__ kb,
    const __bf16* __restrict__ vT, const float* __restrict__ gbuf,
    const float* __restrict__ Mbuf, const float* __restrict__ NFbuf,
    float* __restrict__ hatt) {
  __shared__ __bf16 Ks[64][136];         // [s][d]  17.4 KB
  __shared__ __bf16 Vs[128][72];         // [d][s]  18.4 KB
  __shared__ __bf16 plds[4][2][16][72];  // [wave][tile][t][s] 18.4 KB
  __shared__ float gls[64];
  int px = blockIdx.x, bh = blockIdx.y;
  int tqA = px, tqB = 15 - px;
  int bb = bh >> 2, hh = bh & 3;
  int tid = threadIdx.x;
  int wv = tid >> 6, lane = tid & 63;
  int lg = lane >> 4, li = lane & 15;
  int tbA = tqA * 64 + wv * 16;
  int tbB = tqB * 64 + wv * 16;
  const float scale = 0.08838834764831845f;

  // Q fragments (held for whole kernel)
  bf16x8 aqA[4], aqB[4];
  {
    const __bf16* qpA = qb + ((size_t)(bb * S + tbA + li)) * 512 + hh * 128 + lg * 8;
    const __bf16* qpB = qb + ((size_t)(bb * S + tbB + li)) * 512 + hh * 128 + lg * 8;
    #pragma unroll
    for (int cd = 0; cd < 4; ++cd) {
      aqA[cd] = *(const bf16x8*)(qpA + cd * 32);
      aqB[cd] = *(const bf16x8*)(qpB + cd * 32);
    }
  }
  float mlA[4], nfA[4], mlB[4], nfB[4];
  #pragma unroll
  for (int r = 0; r < 4; ++r) {
    mlA[r] = Mbuf[(size_t)bh * S + tbA + lg * 4 + r];
    nfA[r] = NFbuf[(size_t)bh * S + tbA + lg * 4 + r];
    mlB[r] = Mbuf[(size_t)bh * S + tbB + lg * 4 + r];
    nfB[r] = NFbuf[(size_t)bh * S + tbB + lg * 4 + r];
  }

  floatx4 oA[8], oB[8];
  #pragma unroll
  for (int df = 0; df < 8; ++df) { oA[df] = (floatx4)(0.f); oB[df] = (floatx4)(0.f); }
  float rsA[4] = {0, 0, 0, 0}, rsB[4] = {0, 0, 0, 0};

  int krow = tid >> 3, kcol = tid & 7;  // krow 0..31, kcol 0..7
  bf16x8 kreg[4], vreg[4];
  float greg = 0.f;
  // K tile is 64 s-rows x 128 d: each thread carries 4 bf16x8 covering
  // {s=krow, s=krow+32} x {d=kcol*8, d=64+kcol*8}.  (R3 bug: only d<64 was staged.)
  auto preload = [&](int st) {
    int s0 = st * 64;
    const __bf16* kp = kb + ((size_t)(bb * S + s0 + krow)) * 512 + hh * 128;
    kreg[0] = *(const bf16x8*)(kp + kcol * 8);
    kreg[1] = *(const bf16x8*)(kp + (size_t)32 * 512 + kcol * 8);
    kreg[2] = *(const bf16x8*)(kp + 64 + kcol * 8);
    kreg[3] = *(const bf16x8*)(kp + (size_t)32 * 512 + 64 + kcol * 8);
    #pragma unroll
    for (int i = 0; i < 4; ++i)
      vreg[i] = *(const bf16x8*)(vT + ((size_t)(bh * 128 + krow + i * 32)) * 1024 + s0 + kcol * 8);
    if (tid < 64) greg = gbuf[(size_t)bh * S + s0 + tid];
  };
  preload(0);

  for (int st = 0; st <= tqB; ++st) {
    __syncthreads();
    *(bf16x8*)&Ks[krow][kcol * 8] = kreg[0];
    *(bf16x8*)&Ks[krow + 32][kcol * 8] = kreg[1];
    *(bf16x8*)&Ks[krow][64 + kcol * 8] = kreg[2];
    *(bf16x8*)&Ks[krow + 32][64 + kcol * 8] = kreg[3];
    #pragma unroll
    for (int i = 0; i < 4; ++i) *(bf16x8*)&Vs[krow + i * 32][kcol * 8] = vreg[i];
    if (tid < 64) gls[tid] = greg;
    __syncthreads();
    if (st < tqB) preload(st + 1);

    int s0 = st * 64;
    bool actA = (st <= tqA);
    // ---- QK^T + decay weighting ----
    #pragma unroll
    for (int ns = 0; ns < 4; ++ns) {
      bf16x8 bk0 = *(const bf16x8*)&Ks[ns * 16 + li][lg * 8];
      bf16x8 bk1 = *(const bf16x8*)&Ks[ns * 16 + li][32 + lg * 8];
      bf16x8 bk2 = *(const bf16x8*)&Ks[ns * 16 + li][64 + lg * 8];
      bf16x8 bk3 = *(const bf16x8*)&Ks[ns * 16 + li][96 + lg * 8];
      int s = s0 + ns * 16 + li;
      float gv = gls[ns * 16 + li];
      if (actA) {
        floatx4 pa = (floatx4)(0.f);
        pa = __builtin_amdgcn_mfma_f32_16x16x32_bf16(aqA[0], bk0, pa, 0, 0, 0);
        pa = __builtin_amdgcn_mfma_f32_16x16x32_bf16(aqA[1], bk1, pa, 0, 0, 0);
        pa = __builtin_amdgcn_mfma_f32_16x16x32_bf16(aqA[2], bk2, pa, 0, 0, 0);
        pa = __builtin_amdgcn_mfma_f32_16x16x32_bf16(aqA[3], bk3, pa, 0, 0, 0);
        #pragma unroll
        for (int r = 0; r < 4; ++r) {
          int t = tbA + lg * 4 + r;
          float val = pa[r] * scale * __expf(gv - mlA[r]);
          float w = (s <= t) ? val : 0.f;
          rsA[r] += w;
          plds[wv][0][lg * 4 + r][ns * 16 + li] = (__bf16)w;
        }
      }
      {
        floatx4 pb = (floatx4)(0.f);
        pb = __builtin_amdgcn_mfma_f32_16x16x32_bf16(aqB[0], bk0, pb, 0, 0, 0);
        pb = __builtin_amdgcn_mfma_f32_16x16x32_bf16(aqB[1], bk1, pb, 0, 0, 0);
        pb = __builtin_amdgcn_mfma_f32_16x16x32_bf16(aqB[2], bk2, pb, 0, 0, 0);
        pb = __builtin_amdgcn_mfma_f32_16x16x32_bf16(aqB[3], bk3, pb, 0, 0, 0);
        #pragma unroll
        for (int r = 0; r < 4; ++r) {
          int t = tbB + lg * 4 + r;
          float val = pb[r] * scale * __expf(gv - mlB[r]);
          float w = (s <= t) ? val : 0.f;
          rsB[r] += w;
          plds[wv][1][lg * 4 + r][ns * 16 + li] = (__bf16)w;
        }
      }
    }
    // ---- PV (plds is wave-private: same-wave LDS ops complete in order) ----
    bf16x8 apA0, apA1, apB0, apB1;
    if (actA) {
      apA0 = *(const bf16x8*)&plds[wv][0][li][lg * 8];
      apA1 = *(const bf16x8*)&plds[wv][0][li][32 + lg * 8];
    }
    apB0 = *(const bf16x8*)&plds[wv][1][li][lg * 8];
    apB1 = *(const bf16x8*)&plds[wv][1][li][32 + lg * 8];
    #pragma unroll
    for (int df = 0; df < 8; ++df) {
      bf16x8 bv0 = *(const bf16x8*)&Vs[df * 16 + li][lg * 8];
      bf16x8 bv1 = *(const bf16x8*)&Vs[df * 16 + li][32 + lg * 8];
      if (actA) {
        oA[df] = __builtin_amdgcn_mfma_f32_16x16x32_bf16(apA0, bv0, oA[df], 0, 0, 0);
        oA[df] = __builtin_amdgcn_mfma_f32_16x16x32_bf16(apA1, bv1, oA[df], 0, 0, 0);
      }
      oB[df] = __builtin_amdgcn_mfma_f32_16x16x32_bf16(apB0, bv0, oB[df], 0, 0, 0);
      oB[df] = __builtin_amdgcn_mfma_f32_16x16x32_bf16(apB1, bv1, oB[df], 0, 0, 0);
    }
  }
  // reduce row sums across the 16 col-lanes (bits 0..3)
  #pragma unroll
  for (int r = 0; r < 4; ++r) {
    float a = rsA[r], b = rsB[r];
    a += __shfl_xor(a, 1, 64); a += __shfl_xor(a, 2, 64);
    a += __shfl_xor(a, 4, 64); a += __shfl_xor(a, 8, 64);
    b += __shfl_xor(b, 1, 64); b += __shfl_xor(b, 2, 64);
    b += __shfl_xor(b, 4, 64); b += __shfl_xor(b, 8, 64);
    rsA[r] = a; rsB[r] = b;
  }
  #pragma unroll
  for (int r = 0; r < 4; ++r) {
    float invA = 1.f / (fmaxf(fabsf(rsA[r]), nfA[r]) + 1e-6f);
    float invB = 1.f / (fmaxf(fabsf(rsB[r]), nfB[r]) + 1e-6f);
    float* obA = hatt + ((size_t)(bb * S + tbA + lg * 4 + r)) * 512 + hh * 128 + li;
    float* obB = hatt + ((size_t)(bb * S + tbB + lg * 4 + r)) * 512 + hh * 128 + li;
    #pragma unroll
    for (int df = 0; df < 8; ++df) {
      obA[df * 16] = oA[df][r] * invA;
      obB[df * 16] = oB[df][r] * invB;
    }
  }
}

// ---------------- GroupNorm + skip*xc + *silu(z): hatt f32 -> hd bf16 ----------------
__global__ __launch_bounds__(512) void gn_kernel(
    const float* __restrict__ hatt, const float* __restrict__ gg,
    const float* __restrict__ gb, const float* __restrict__ skip,
    const __bf16* __restrict__ xc, const __bf16* __restrict__ up,
    __bf16* __restrict__ hd) {
  int row = blockIdx.x, tid = threadIdx.x;
  int head = tid >> 7;
  __shared__ float red[8];
  float v = hatt[(size_t)row * 512 + tid];
  float s = wave_sum(v);
  int wid = tid >> 6, lane = tid & 63;
  if (lane == 0) red[wid] = s;
  __syncthreads();
  float mu = (red[head * 2] + red[head * 2 + 1]) * (1.f / 128.f);
  __syncthreads();
  float d = v - mu;
  float s2 = wave_sum(d * d);
  if (lane == 0) red[wid] = s2;
  __syncthreads();
  float var = (red[head * 2] + red[head * 2 + 1]) * (1.f / 128.f);
  float rsq = rsqrtf(var + 1e-5f);
  float ln = d * rsq * gg[tid] + gb[tid];
  float val = ln + skip[tid] * (float)xc[(size_t)row * 512 + tid];
  float z = (float)up[(size_t)row * 1024 + 512 + tid];
  float sg = 1.f / (1.f + expf(-z));
  hd[(size_t)row * 512 + tid] = (__bf16)(val * (z * sg));
}

// ---------------- final LN + head ----------------
__global__ __launch_bounds__(256) void final_kernel(
    const float* __restrict__ h, const float* __restrict__ g,
    const float* __restrict__ b, const float* __restrict__ Wf,
    const float* __restrict__ bf, float* __restrict__ out) {
  int bb = blockIdx.x, tid = threadIdx.x;
  size_t row = (size_t)(bb * S + S - 1) * 256;
  __shared__ float red[4];
  float v = h[row + tid];
  float s = wave_sum(v);
  int wid = tid >> 6, lane = tid & 63;
  if (lane == 0) red[wid] = s;
  __syncthreads();
  float mu = (red[0] + red[1] + red[2] + red[3]) * (1.f / 256.f);
  __syncthreads();
  float d = v - mu;
  float s2 = wave_sum(d * d);
  if (lane == 0) red[wid] = s2;
  __syncthreads();
  float var = (red[0] + red[1] + red[2] + red[3]) * (1.f / 256.f);
  float rs = rsqrtf(var + 1e-5f);
  float ln = d * rs * g[tid] + b[tid];
  float p = ln * Wf[tid];
  float psum = wave_sum(p);
  __syncthreads();
  if (lane == 0) red[wid] = psum;
  __syncthreads();
  if (tid == 0) out[bb] = red[0] + red[1] + red[2] + red[3] + bf[0];
}

extern "C" void kernel_launch(void* const* d_in, const int* in_sizes, int n_in,
                              void* d_out, int out_size, void* d_ws, size_t ws_size,
                              hipStream_t stream) {
  const float* x      = (const float*)d_in[0];
  const float* tf     = (const float*)d_in[1];
  const float* Wp     = (const float*)d_in[2];
  const float* bp     = (const float*)d_in[3];
  const float* ln_g   = (const float*)d_in[4];
  const float* ln_b   = (const float*)d_in[5];
  const float* Wup    = (const float*)d_in[6];
  const float* bup    = (const float*)d_in[7];
  const float* conv_w = (const float*)d_in[8];
  const float* conv_b = (const float*)d_in[9];
  const float* Wq     = (const float*)d_in[10];
  const float* Wk     = (const float*)d_in[11];
  const float* Wv     = (const float*)d_in[12];
  const float* Wif    = (const float*)d_in[13];
  const float* bif    = (const float*)d_in[14];
  const float* gn_g   = (const float*)d_in[15];
  const float* gn_b   = (const float*)d_in[16];
  const float* skip   = (const float*)d_in[17];
  const float* Wdown  = (const float*)d_in[18];
  const float* bdown  = (const float*)d_in[19];
  const float* lnf_g  = (const float*)d_in[20];
  const float* lnf_b  = (const float*)d_in[21];
  const float* Wf     = (const float*)d_in[22];
  const float* bf     = (const float*)d_in[23];
  float* out = (float*)d_out;

  float* h     = (float*)d_ws;            // 2,097,152 f32
  float* hatt  = h + 2097152;             // 4,194,304 f32
  float* gates = hatt + 4194304;          // 65,536 f32
  float* gbuf  = gates + 65536;           // 32,768
  float* Mbuf  = gbuf + 32768;            // 32,768
  float* NFbuf = Mbuf + 32768;            // 32,768
  __bf16* hn   = (__bf16*)(NFbuf + 32768);  // 2,097,152 bf16
  __bf16* up   = hn + 2097152;            // 8,388,608
  __bf16* xc   = up + 8388608;            // 4,194,304
  __bf16* qbuf = xc + 4194304;            // 4,194,304
  __bf16* kbuf = qbuf + 4194304;          // 4,194,304
  __bf16* vbuf = kbuf + 4194304;          // 4,194,304
  __bf16* vT   = vbuf + 4194304;          // 4,194,304
  __bf16* hd   = vT + 4194304;            // 4,194,304
  __bf16* WupT   = hd + 4194304;          // 1,048,576
  __bf16* WqT    = WupT + 1048576;        // 1,048,576
  __bf16* WkT    = WqT + 1048576;         // 1,048,576
  __bf16* WvT    = WkT + 1048576;         // 1,048,576
  __bf16* WdownT = WvT + 1048576;         // 524,288

  wtrans_kernel<<<4608, 256, 0, stream>>>(Wup, Wq, Wk, Wv, Wdown,
                                          WupT, WqT, WkT, WvT, WdownT);
  embed_kernel<<<8192, 256, 0, stream>>>(x, tf, Wp, bp, h);
  for (int l = 0; l < NLAYER; ++l) {
    ln256_kernel<<<8192, 256, 0, stream>>>(h, ln_g + l * 256, ln_b + l * 256, hn);
    hgemm<1, 0><<<dim3(8, 64), 256, 0, stream>>>(
        hn, 256, WupT + (size_t)l * 262144, 256, bup + l * 1024, up, 1024);
    conv_silu_kernel<<<16384, 256, 0, stream>>>(up, conv_w + l * 2048, conv_b + l * 512, xc);
    hgemm<1, 0><<<dim3(4, 64), 256, 0, stream>>>(
        xc, 512, WqT + (size_t)l * 262144, 512, nullptr, qbuf, 512);
    hgemm<1, 0><<<dim3(4, 64), 256, 0, stream>>>(
        xc, 512, WkT + (size_t)l * 262144, 512, nullptr, kbuf, 512);
    hgemm<1, 0><<<dim3(4, 64), 256, 0, stream>>>(
        up, 1024, WvT + (size_t)l * 262144, 512, nullptr, vbuf, 512);
    gates_kernel<<<8192, 256, 0, stream>>>(qbuf, kbuf, vbuf, Wif + (size_t)l * 1536 * 8,
                                           bif + l * 8, gates);
    scan_kernel<<<32, 1024, 0, stream>>>(gates, gbuf, Mbuf, NFbuf);
    vtrans_kernel<<<1024, 256, 0, stream>>>(vbuf, vT);
    attn_kernel<<<dim3(8, 32), 256, 0, stream>>>(qbuf, kbuf, vT, gbuf, Mbuf, NFbuf, hatt);
    gn_kernel<<<8192, 512, 0, stream>>>(hatt, gn_g + l * 512, gn_b + l * 512,
                                        skip + l * 512, xc, up, hd);
    hgemm<0, 1><<<dim3(2, 64), 256, 0, stream>>>(
        hd, 512, WdownT + (size_t)l * 131072, 512, bdown + l * 256, h, 256);
  }
  final_kernel<<<8, 256, 0, stream>>>(h, lnf_g, lnf_b, Wf, bf, out);
}